// Round 6
// baseline (233.216 us; speedup 1.0000x reference)
//
#include <hip/hip_runtime.h>
#include <cmath>

// Problem constants
#define B_TOTAL 262144
#define D 16
#define TE 3
#define H 64

#define TILES_PER_BLOCK 16
#define FLUSH_GROUP 4
#define NBLOCKS (B_TOTAL / 16 / TILES_PER_BLOCK)   // 1024

#define LOG2E 1.44269504088896340736f
#define LN2   0.693147180559945309417f

// f16 transpose buffer row stride (in f16 elements). 72 = 64 + 8 pad:
// breaks power-of-2 bank aliasing; b128 reads stay 16B-aligned
// ((lm*72 + 8q)*2 % 16 == 0). Proven pattern from R3 (3.7M conflict cyc).
#define RSH 72

typedef _Float16 half8  __attribute__((ext_vector_type(8)));
typedef __fp16   fp16x2 __attribute__((ext_vector_type(2)));   // cvt_pkrtz return type
typedef float    f32x4  __attribute__((ext_vector_type(4)));
typedef unsigned int uint32;

// log2-domain softplus: log2(1 + 2^xs). Scale factors pre-folded into weights:
// W1,b1,b2 carry log2e; W3 carries ln2; ln2*log2e==1 so W2 is raw.
__device__ __forceinline__ float sp_log2(float xs) {
    return __builtin_amdgcn_logf(1.0f + __builtin_amdgcn_exp2f(xs));
}
// exact softplus for the final (unscaled) output
__device__ __forceinline__ float softplus_full(float x) {
    float e = __builtin_amdgcn_exp2f(-fabsf(x) * LOG2E);
    return fmaxf(x, 0.0f) + LN2 * __builtin_amdgcn_logf(1.0f + e);
}

// 16 waves/block; wave w owns dim d=w. Per 16-row tile: L1 MFMA (bias folded
// via constant-1 input column) -> softplus -> f16 LDS transpose -> L2 MFMA ->
// softplus -> same transpose -> L3 MFMA (replicated-column W3 B-frag) -> out.
// LDS kept at 45KB so 2 blocks (= 32 waves, HW cap) are resident per CU.
__global__ __launch_bounds__(1024, 4) void DiagonalVariance_kernel(
    const float* __restrict__ t,   // [B, TE]
    const float* __restrict__ y,   // [B, D]
    const float* __restrict__ W1,  // [D, 4, 64]
    const float* __restrict__ b1,  // [D, 64]
    const float* __restrict__ W2,  // [D, 64, 64]
    const float* __restrict__ b2,  // [D, 64]
    const float* __restrict__ W3,  // [D, 64, 1]
    const float* __restrict__ b3,  // [D, 1]
    float* __restrict__ out)       // [B, D]
{
    __shared__ __align__(16) _Float16 tbuf[D * 16 * RSH];   // 36.9 KB
    __shared__ float obuf[2][FLUSH_GROUP * 256];            // 8 KB double-buffered

    const int wave = threadIdx.x >> 6;   // = d
    const int lane = threadIdx.x & 63;
    const int q    = lane >> 4;
    const int lm   = lane & 15;
    const int d    = wave;
    const bool q0  = (q == 0);

    const float* __restrict__ W1d = W1 + d * (4 * H);
    const float* __restrict__ b1d = b1 + d * H;
    const float* __restrict__ W2d = W2 + d * (H * H);
    const float* __restrict__ b2d = b2 + d * H;
    const float* __restrict__ W3d = W3 + d * H;

    // ---------------- one-time per-wave fragment setup ----------------
    // W2 B-frags (raw): B[n=16nt+lm][k=32ks+8q+j]
    half8 w2f[2][4];
    #pragma unroll
    for (int ks = 0; ks < 2; ++ks)
        #pragma unroll
        for (int nt = 0; nt < 4; ++nt)
            #pragma unroll
            for (int j = 0; j < 8; ++j)
                w2f[ks][nt][j] = (_Float16)W2d[(32 * ks + 8 * q + j) * H + 16 * nt + lm];

    // W1 B-frags (scaled by log2e), bias b1*log2e in the k=4 row; zero rows
    // k=5..31 make the A-side garbage lanes harmless.
    half8 w1f[4];
    #pragma unroll
    for (int nt = 0; nt < 4; ++nt) {
        #pragma unroll
        for (int j = 0; j < 8; ++j) {
            const int h = 16 * nt + lm;
            float v = 0.0f;
            if (q0 && j < 4)  v = W1d[j * H + h] * LOG2E;
            if (q0 && j == 4) v = b1d[h] * LOG2E;
            w1f[nt][j] = (_Float16)v;
        }
    }

    // W3 B-frag (scaled by ln2), replicated across all n columns.
    half8 w3f[2];
    #pragma unroll
    for (int ks = 0; ks < 2; ++ks)
        #pragma unroll
        for (int j = 0; j < 8; ++j)
            w3f[ks][j] = (_Float16)(W3d[32 * ks + 8 * q + j] * LN2);

    // b2 (scaled) as C-init fragments: col=16nt+lm, replicated over rows.
    f32x4 b2f[4];
    #pragma unroll
    for (int nt = 0; nt < 4; ++nt) {
        const float bv = b2d[16 * nt + lm] * LOG2E;
        b2f[nt] = (f32x4){bv, bv, bv, bv};
    }
    const float b3v = b3[d];

    // f16 LDS transpose bases (per-wave slice, immediate offsets per access)
    _Float16* const tb  = tbuf + wave * (16 * RSH);
    _Float16* const twr = tb + (q * 4) * RSH + lm;       // + r*RSH + nt*16
    const _Float16* const trd = tb + lm * RSH + 8 * q;   // + 32*ks

    #pragma unroll 1
    for (int g = 0; g < TILES_PER_BLOCK / FLUSH_GROUP; ++g) {
        float* const ob = obuf[g & 1];
        #pragma unroll 1
        for (int tg = 0; tg < FLUSH_GROUP; ++tg) {
            const int tile = blockIdx.x * TILES_PER_BLOCK + g * FLUSH_GROUP + tg;
            const int row  = tile * 16 + lm;

            // ---- A-frag: k = [y, t0, t1, t2, 1(bias), 0,...] (quad-0 rows of
            // B are the only nonzero ones, so no lane masking needed) ----
            const float* tp = t + row * TE;
            const float x0 = y[row * D + d];
            const float t0 = tp[0];
            const float t1 = tp[1];
            const float t2 = tp[2];
            union { half8 h; fp16x2 p[4]; uint32 u[4]; } af;
            af.p[0] = __builtin_amdgcn_cvt_pkrtz(x0, t0);
            af.p[1] = __builtin_amdgcn_cvt_pkrtz(t1, t2);
            af.u[2] = 0x00003C00u;   // {1.0h, 0h} — bias multiplier at k=4
            af.u[3] = 0u;

            // ---- layer 1: acc1 = (x*W1 + b1)*log2e, C = 0 ----
            f32x4 acc1[4];
            #pragma unroll
            for (int nt = 0; nt < 4; ++nt)
                acc1[nt] = __builtin_amdgcn_mfma_f32_16x16x32_f16(
                    af.h, w1f[nt], (f32x4){0.f, 0.f, 0.f, 0.f}, 0, 0, 0);

            // ---- softplus (log2 domain) -> f16 LDS transpose (C -> A layout) ----
            #pragma unroll
            for (int nt = 0; nt < 4; ++nt)
                #pragma unroll
                for (int r = 0; r < 4; ++r)
                    twr[r * RSH + nt * 16] = (_Float16)sp_log2(acc1[nt][r]);

            // ---- layer-2 A-frags straight from LDS (no cvt) ----
            half8 a2[2];
            #pragma unroll
            for (int ks = 0; ks < 2; ++ks)
                a2[ks] = *(const half8*)(trd + 32 * ks);

            // ---- layer 2: C-init = b2*log2e ----
            f32x4 acc2[4];
            #pragma unroll
            for (int nt = 0; nt < 4; ++nt)
                acc2[nt] = __builtin_amdgcn_mfma_f32_16x16x32_f16(a2[0], w2f[0][nt], b2f[nt], 0, 0, 0);
            #pragma unroll
            for (int nt = 0; nt < 4; ++nt)
                acc2[nt] = __builtin_amdgcn_mfma_f32_16x16x32_f16(a2[1], w2f[1][nt], acc2[nt], 0, 0, 0);

            // ---- softplus -> same LDS transpose (same-wave DS ordering) ----
            #pragma unroll
            for (int nt = 0; nt < 4; ++nt)
                #pragma unroll
                for (int r = 0; r < 4; ++r)
                    twr[r * RSH + nt * 16] = (_Float16)sp_log2(acc2[nt][r]);

            half8 a3[2];
            #pragma unroll
            for (int ks = 0; ks < 2; ++ks)
                a3[ks] = *(const half8*)(trd + 32 * ks);

            // ---- layer 3: every column of D3 = sum_k L[b,k]*W3[k]*ln2 ----
            f32x4 acc3;
            acc3 = __builtin_amdgcn_mfma_f32_16x16x32_f16(a3[0], w3f[0], (f32x4){0.f, 0.f, 0.f, 0.f}, 0, 0, 0);
            acc3 = __builtin_amdgcn_mfma_f32_16x16x32_f16(a3[1], w3f[1], acc3, 0, 0, 0);

            // lane lm<4 takes reg r=lm -> row q*4+lm; all 16 rows covered.
            const float v01 = (lm & 1) ? acc3[1] : acc3[0];
            const float v23 = (lm & 1) ? acc3[3] : acc3[2];
            const float vs  = (lm & 2) ? v23 : v01;
            if (lm < 4)
                ob[tg * 256 + (q * 4 + lm) * D + d] = softplus_full(vs + b3v);
        }

        // Single barrier per group: ensures all waves wrote group g before the
        // flush-read. Next group's staging goes to the other obuf half, and any
        // wave's read here precedes its arrival at the next group's barrier,
        // so the write-after-read hazard on this half is ordered by that barrier.
        __syncthreads();
        out[blockIdx.x * (TILES_PER_BLOCK * 256) + g * 1024 + threadIdx.x] = ob[threadIdx.x];
    }
}

extern "C" void kernel_launch(void* const* d_in, const int* in_sizes, int n_in,
                              void* d_out, int out_size, void* d_ws, size_t ws_size,
                              hipStream_t stream) {
    const float* t  = (const float*)d_in[0];
    const float* y  = (const float*)d_in[1];
    const float* W1 = (const float*)d_in[2];
    const float* b1 = (const float*)d_in[3];
    const float* W2 = (const float*)d_in[4];
    const float* b2 = (const float*)d_in[5];
    const float* W3 = (const float*)d_in[6];
    const float* b3 = (const float*)d_in[7];
    float* out = (float*)d_out;

    DiagonalVariance_kernel<<<dim3(NBLOCKS), dim3(1024), 0, stream>>>(
        t, y, W1, b1, W2, b2, W3, b3, out);
}